// Round 11
// baseline (411.497 us; speedup 1.0000x reference)
//
#include <hip/hip_runtime.h>
#include <hip/hip_bf16.h>
#include <math.h>

// Problem constants (fixed by the reference).
constexpr int Bb = 8;
constexpr int Cc = 256;
constexpr int Hh = 4;
constexpr int Nn = 2048;
constexpr int Mm = 2048;
constexpr size_t BCN = (size_t)Bb * Cc * Nn;   // 4,194,304 elements

typedef __attribute__((ext_vector_type(8))) short short8;
typedef __attribute__((ext_vector_type(4))) float f32x4;

__device__ __forceinline__ unsigned short bfu(float x) {
  __hip_bfloat16 b = __float2bfloat16(x);        // RNE
  return __builtin_bit_cast(unsigned short, b);
}

__device__ __forceinline__ void gload16(const unsigned short* g, unsigned short* l) {
  __builtin_amdgcn_global_load_lds(
      (const __attribute__((address_space(1))) unsigned int*)g,
      (__attribute__((address_space(3))) unsigned int*)l, 16, 0, 0);
}

// ---------------------------------------------------------------------------
// Weight quantization: f32 -> bf16 (Wq scaled by 0.125). One launch, 6 segs.
// ---------------------------------------------------------------------------
__global__ __launch_bounds__(256) void quantw_kernel(
    const float* __restrict__ s0, const float* __restrict__ s1,
    const float* __restrict__ s2, const float* __restrict__ s3,
    const float* __restrict__ s4, const float* __restrict__ s5,
    unsigned short* __restrict__ d0, unsigned short* __restrict__ d1,
    unsigned short* __restrict__ d2, unsigned short* __restrict__ d3,
    unsigned short* __restrict__ d4, unsigned short* __restrict__ d5)
{
  const int seg = blockIdx.y;
  const float* s; unsigned short* d; int cnt; float sc = 1.f;
  switch (seg) {
    case 0: s = s0; d = d0; cnt = 65536;  sc = 0.125f; break;
    case 1: s = s1; d = d1; cnt = 65536;  break;
    case 2: s = s2; d = d2; cnt = 65536;  break;
    case 3: s = s3; d = d3; cnt = 65536;  break;
    case 4: s = s4; d = d4; cnt = 262144; break;
    default: s = s5; d = d5; cnt = 131072; break;
  }
  for (int i = blockIdx.x * 256 + threadIdx.x; i < cnt / 4; i += 64 * 256) {
    float4 v = ((const float4*)s)[i];
    unsigned int lo = bfu(v.x * sc) | ((unsigned int)bfu(v.y * sc) << 16);
    unsigned int hi = bfu(v.z * sc) | ((unsigned int)bfu(v.w * sc) << 16);
    ((uint2*)d)[i] = make_uint2(lo, hi);
  }
}

// ---------------------------------------------------------------------------
// Transpose+quantize: desc [b][256][2048] f32 -> [b][2048][256] bf16.
// ---------------------------------------------------------------------------
__global__ __launch_bounds__(256) void trans_kernel(
    const float* __restrict__ S1, const float* __restrict__ S2,
    unsigned short* __restrict__ D1, unsigned short* __restrict__ D2)
{
  __shared__ float T[64][65];
  const int z = blockIdx.z, b = z & 7;
  const float* S = (z >> 3) ? S2 : S1;
  unsigned short* D = (z >> 3) ? D2 : D1;
  const int n0 = blockIdx.x * 64, c0 = blockIdx.y * 64;
  const int t = threadIdx.x, t4 = t >> 6, tl = t & 63;

  #pragma unroll
  for (int r = 0; r < 16; ++r) {
    int cl = r * 4 + t4;
    T[cl][tl] = S[((size_t)b * 256 + c0 + cl) * 2048 + n0 + tl];
  }
  __syncthreads();
  #pragma unroll
  for (int r = 0; r < 16; ++r) {
    int nl = r * 4 + t4;
    D[((size_t)b * 2048 + n0 + nl) * 256 + c0 + tl] = bfu(T[tl][nl]);
  }
}

// ---------------------------------------------------------------------------
// Staged bf16 MFMA GEMM (round-7 verified): 128x128 tile, BK=64, 4 waves,
// global_load_lds staging with K-group XOR swizzle (pre-swizzled source,
// linear LDS dest, swizzled ds_read).
// EPI: 0 = Q/K (bf16 [b*H+h][n][64], bias*oscale)
//      1 = V   (bf16 [b][o][m], (acc+bias)*weight_v[b][m])
//      2 = M   (bf16 [b][n][256], +bias)
//      3 = C1  (bf16 [b][n][512], BN+ReLU)
//      4 = C2  (f32 [b][o][n], +bias+residual)
// ---------------------------------------------------------------------------
template<int K1, int K2, int COUT, int EPI>
__global__ __launch_bounds__(256) void gemm_kernel(
    const unsigned short* __restrict__ Wb,
    const unsigned short* __restrict__ X1, const unsigned short* __restrict__ X2,
    const float* __restrict__ bias,
    const float* __restrict__ p0, const float* __restrict__ p1,
    const float* __restrict__ p2, const float* __restrict__ p3,
    void* __restrict__ Yv, float oscale)
{
  constexpr int KT = K1 + K2;
  constexpr bool TRANS = (EPI == 0 || EPI == 2 || EPI == 3);
  __shared__ unsigned short lds[2 * 128 * 64];
  unsigned short* Wl = lds;
  unsigned short* Xl = lds + 128 * 64;

  const int t = threadIdx.x;
  const int w = t >> 6, l = t & 63;
  const int c = l & 15, h4 = l >> 4;
  const int n0 = blockIdx.x * 128;
  const int o0 = blockIdx.y * 128;
  const int b  = blockIdx.z;
  const int wo = (w & 1) * 64, wn = (w >> 1) * 64;

  const int r8  = t >> 3;               // row within chunk
  const int kgx = (t & 7) ^ (r8 & 7);   // pre-swizzled k-group (involution)

  const unsigned short* Xb1 = X1 + (size_t)b * 2048 * K1;

  f32x4 acc[4][4] = {};

  #pragma unroll 1
  for (int kt = 0; kt < KT / 64; ++kt) {
    __syncthreads();
    #pragma unroll
    for (int q = 0; q < 4; ++q) {
      int row = q * 32 + r8;
      gload16(Wb + (size_t)(o0 + row) * KT + kt * 64 + kgx * 8,
              Wl + q * 2048 + w * 512);
      const unsigned short* src;
      if constexpr (K2 == 0) {
        src = Xb1 + (size_t)(n0 + row) * K1 + kt * 64 + kgx * 8;
      } else {
        src = (kt * 64 < K1)
          ? Xb1 + (size_t)(n0 + row) * K1 + kt * 64 + kgx * 8
          : X2 + ((size_t)b * 2048 + n0 + row) * K2 + (kt * 64 - K1) + kgx * 8;
      }
      gload16(src, Xl + q * 2048 + w * 512);
    }
    __syncthreads();

    #pragma unroll
    for (int kk = 0; kk < 2; ++kk) {
      short8 wf[4], xf[4];
      #pragma unroll
      for (int f = 0; f < 4; ++f) {
        int row = wo + f * 16 + c;
        wf[f] = *(const short8*)((const char*)Wl + row * 128 + (((kk * 4 + h4) ^ (row & 7)) << 4));
      }
      #pragma unroll
      for (int f = 0; f < 4; ++f) {
        int row = wn + f * 16 + c;
        xf[f] = *(const short8*)((const char*)Xl + row * 128 + (((kk * 4 + h4) ^ (row & 7)) << 4));
      }
      #pragma unroll
      for (int i = 0; i < 4; ++i)
        #pragma unroll
        for (int j = 0; j < 4; ++j) {
          if constexpr (TRANS)
            acc[i][j] = __builtin_amdgcn_mfma_f32_16x16x32_bf16(xf[i], wf[j], acc[i][j], 0, 0, 0);
          else
            acc[i][j] = __builtin_amdgcn_mfma_f32_16x16x32_bf16(wf[i], xf[j], acc[i][j], 0, 0, 0);
        }
    }
  }

  if constexpr (EPI == 0) {             // Qt/Kt: [b*H+h][n][64] bf16
    unsigned short* Y = (unsigned short*)Yv;
    #pragma unroll
    for (int j = 0; j < 4; ++j) {
      int og = o0 + wo + j * 16 + c;
      float bb = bias[og] * oscale;
      int hh = og >> 6, d = og & 63;
      unsigned short* Yp = Y + (((size_t)b * Hh + hh) * 2048) * 64 + d;
      #pragma unroll
      for (int i = 0; i < 4; ++i)
        #pragma unroll
        for (int r = 0; r < 4; ++r) {
          int ng = n0 + wn + i * 16 + h4 * 4 + r;
          Yp[(size_t)ng * 64] = bfu(acc[i][j][r] + bb);
        }
    }
  } else if constexpr (EPI == 2) {      // MoutT: [b][n][256] bf16
    unsigned short* Y = (unsigned short*)Yv;
    #pragma unroll
    for (int j = 0; j < 4; ++j) {
      int og = o0 + wo + j * 16 + c;
      float bb = bias[og];
      #pragma unroll
      for (int i = 0; i < 4; ++i)
        #pragma unroll
        for (int r = 0; r < 4; ++r) {
          int ng = n0 + wn + i * 16 + h4 * 4 + r;
          Y[((size_t)b * 2048 + ng) * 256 + og] = bfu(acc[i][j][r] + bb);
        }
    }
  } else if constexpr (EPI == 3) {      // HT: [b][n][512] bf16, BN+ReLU
    unsigned short* Y = (unsigned short*)Yv;
    #pragma unroll
    for (int j = 0; j < 4; ++j) {
      int og = o0 + wo + j * 16 + c;
      float bb  = bias[og];
      float inv = p0[og] / sqrtf(p3[og] + 1e-5f);
      float add = p1[og] - p2[og] * inv;
      #pragma unroll
      for (int i = 0; i < 4; ++i)
        #pragma unroll
        for (int r = 0; r < 4; ++r) {
          int ng = n0 + wn + i * 16 + h4 * 4 + r;
          float v = fmaxf((acc[i][j][r] + bb) * inv + add, 0.f);
          Y[((size_t)b * 2048 + ng) * 512 + og] = bfu(v);
        }
    }
  } else if constexpr (EPI == 1) {      // Vb: [b][o][m] bf16, *weight_v
    unsigned short* Y = (unsigned short*)Yv;
    #pragma unroll
    for (int j = 0; j < 4; ++j) {
      int mg = n0 + wn + j * 16 + c;
      float sc = p0[(size_t)b * 2048 + mg];
      #pragma unroll
      for (int i = 0; i < 4; ++i)
        #pragma unroll
        for (int r = 0; r < 4; ++r) {
          int og = o0 + wo + i * 16 + h4 * 4 + r;
          Y[((size_t)b * 256 + og) * 2048 + mg] = bfu((acc[i][j][r] + bias[og]) * sc);
        }
    }
  } else {                              // out: [b][o][n] f32, +bias+residual
    float* Y = (float*)Yv;
    #pragma unroll
    for (int j = 0; j < 4; ++j) {
      int ng = n0 + wn + j * 16 + c;
      #pragma unroll
      for (int i = 0; i < 4; ++i)
        #pragma unroll
        for (int r = 0; r < 4; ++r) {
          int og = o0 + wo + i * 16 + h4 * 4 + r;
          size_t idx = ((size_t)b * 256 + og) * 2048 + ng;
          Y[idx] = acc[i][j][r] + bias[og] + p0[idx];
        }
    }
  }
}

// ---------------------------------------------------------------------------
// MFMA flash attention, 16 n-cols/wave (round-11: doubled TLP vs verified v1;
// math/layout identical to v1 with the j-loop collapsed).
// Wave = 16 n x all m; block = 4 independent waves; grid 1024 (4 blocks/CU,
// 4 waves/SIMD). Swapped QK^T -> lane-local softmax; per-wave swizzled P LDS.
// ---------------------------------------------------------------------------
__global__ __launch_bounds__(256, 4) void attn_mfma_kernel(
    const unsigned short* __restrict__ Qt, const unsigned short* __restrict__ Kt,
    const unsigned short* __restrict__ Vb, unsigned short* __restrict__ Ot)
{
  // XCD-major decode: 4 bh per XCD, 32 n-blocks each.
  const int id  = blockIdx.x;          // 0..1023
  const int xcd = id & 7;
  const int s8  = id >> 3;             // 0..127
  const int bh  = xcd + 8 * (s8 >> 5);
  const int nb  = s8 & 31;
  const int wv  = threadIdx.x >> 6;
  const int l   = threadIdx.x & 63;
  const int c   = l & 15;
  const int h   = l >> 4;
  const int n0  = nb * 64 + wv * 16;

  const unsigned short* Qw = Qt + ((size_t)bh * Nn + n0) * 64;
  const unsigned short* Kb = Kt + (size_t)bh * Mm * 64;
  const unsigned short* Vw = Vb + (size_t)bh * 64 * Mm;

  __shared__ unsigned short Pl[4][16 * 64];     // per-wave P [16n][64m] bf16
  char* P = (char*)Pl[wv];

  // Q B-frags: col n = c, k d = ks*32 + h*8 + i
  short8 qf[2];
  #pragma unroll
  for (int ks = 0; ks < 2; ++ks)
    qf[ks] = *(const short8*)(Qw + (size_t)c * 64 + ks * 32 + h * 8);

  f32x4 acc[4];                        // O^ [dblk]; rows d, col n=c
  #pragma unroll
  for (int d = 0; d < 4; ++d) acc[d] = (f32x4){0.f, 0.f, 0.f, 0.f};
  float rowM = -1e30f, rowL = 0.f;

  #pragma unroll 1
  for (int m0 = 0; m0 < Mm; m0 += 64) {
    // K A-frags: row m = m0+g*16+c, k d = ks*32 + h*8 + i
    short8 kf[4][2];
    #pragma unroll
    for (int g = 0; g < 4; ++g)
      #pragma unroll
      for (int ks = 0; ks < 2; ++ks)
        kf[g][ks] = *(const short8*)(Kb + ((size_t)(m0 + g * 16 + c)) * 64 + ks * 32 + h * 8);

    // S^T[m][n=c]: lane holds rows m = m0 + g*16 + h*4 + r
    f32x4 sc4[4];
    #pragma unroll
    for (int g = 0; g < 4; ++g) {
      f32x4 z = (f32x4){0.f, 0.f, 0.f, 0.f};
      z = __builtin_amdgcn_mfma_f32_16x16x32_bf16(kf[g][0], qf[0], z, 0, 0, 0);
      z = __builtin_amdgcn_mfma_f32_16x16x32_bf16(kf[g][1], qf[1], z, 0, 0, 0);
      sc4[g] = z;
    }

    // V A-frags issued before softmax (latency hides under it).
    short8 vf[4][2];
    #pragma unroll
    for (int db = 0; db < 4; ++db)
      #pragma unroll
      for (int ks = 0; ks < 2; ++ks)
        vf[db][ks] = *(const short8*)(Vw + ((size_t)(db * 16 + c)) * Mm + m0 + ks * 32 + h * 8);

    // Online softmax: lane-local over 16 m + shfl across h-lanes.
    float mx = -1e30f;
    #pragma unroll
    for (int g = 0; g < 4; ++g)
      #pragma unroll
      for (int r = 0; r < 4; ++r) mx = fmaxf(mx, sc4[g][r]);
    mx = fmaxf(mx, __shfl_xor(mx, 16));
    mx = fmaxf(mx, __shfl_xor(mx, 32));
    float nm = fmaxf(rowM, mx);
    float corr = __expf(rowM - nm);
    rowM = nm;
    float sum = 0.f;
    #pragma unroll
    for (int g = 0; g < 4; ++g)
      #pragma unroll
      for (int r = 0; r < 4; ++r) {
        float e = __expf(sc4[g][r] - nm);
        sc4[g][r] = e;
        sum += e;
      }
    sum += __shfl_xor(sum, 16);
    sum += __shfl_xor(sum, 32);
    rowL = rowL * corr + sum;
    #pragma unroll
    for (int db = 0; db < 4; ++db)
      #pragma unroll
      for (int r = 0; r < 4; ++r) acc[db][r] *= corr;

    // P write: row n = c, 4 consecutive m = g*16 + h*4 + r -> b64 (swizzled)
    #pragma unroll
    for (int g = 0; g < 4; ++g) {
      unsigned int lo = ((unsigned int)bfu(sc4[g][1]) << 16) | bfu(sc4[g][0]);
      unsigned int hi = ((unsigned int)bfu(sc4[g][3]) << 16) | bfu(sc4[g][2]);
      int off = c * 128 + ((g * 32 + h * 8) ^ ((c & 7) << 4));
      *(uint2*)(P + off) = make_uint2(lo, hi);
    }

    // PV: B-frag from P (col n = c, k m = ks*32 + h*8), A = V frags.
    short8 pf[2];
    #pragma unroll
    for (int ks = 0; ks < 2; ++ks) {
      int off = c * 128 + ((ks * 64 + h * 16) ^ ((c & 7) << 4));
      pf[ks] = *(const short8*)(P + off);
    }
    #pragma unroll
    for (int db = 0; db < 4; ++db) {
      acc[db] = __builtin_amdgcn_mfma_f32_16x16x32_bf16(vf[db][0], pf[0], acc[db], 0, 0, 0);
      acc[db] = __builtin_amdgcn_mfma_f32_16x16x32_bf16(vf[db][1], pf[1], acc[db], 0, 0, 0);
    }
  }

  const float invl = 1.f / rowL;
  // Ot[b][n][256] bf16, channel = (bh&3)*64 + db*16 + h*4 + r -> 8B stores
  unsigned short* Ob = Ot + ((size_t)(bh >> 2) * Nn) * 256 + (bh & 3) * 64;
  #pragma unroll
  for (int db = 0; db < 4; ++db) {
    unsigned int lo = ((unsigned int)bfu(acc[db][1] * invl) << 16) | bfu(acc[db][0] * invl);
    unsigned int hi = ((unsigned int)bfu(acc[db][3] * invl) << 16) | bfu(acc[db][2] * invl);
    *(uint2*)(Ob + (size_t)(n0 + c) * 256 + db * 16 + h * 4) = make_uint2(lo, hi);
  }
}

// ---------------------------------------------------------------------------
extern "C" void kernel_launch(void* const* d_in, const int* in_sizes, int n_in,
                              void* d_out, int out_size, void* d_ws, size_t ws_size,
                              hipStream_t stream)
{
  (void)in_sizes; (void)n_in; (void)out_size; (void)ws_size;
  const float* desc1 = (const float*)d_in[0];
  const float* desc2 = (const float*)d_in[1];
  const float* wvv   = (const float*)d_in[2];
  const float* Wq  = (const float*)d_in[3];  const float* bq  = (const float*)d_in[4];
  const float* Wk  = (const float*)d_in[5];  const float* bk  = (const float*)d_in[6];
  const float* Wv  = (const float*)d_in[7];  const float* bv  = (const float*)d_in[8];
  const float* Wm  = (const float*)d_in[9];  const float* bm  = (const float*)d_in[10];
  const float* Wc1 = (const float*)d_in[11]; const float* bc1 = (const float*)d_in[12];
  const float* bng = (const float*)d_in[13]; const float* bnb = (const float*)d_in[14];
  const float* bnm = (const float*)d_in[15]; const float* bnv = (const float*)d_in[16];
  const float* Wc2 = (const float*)d_in[17]; const float* bc2 = (const float*)d_in[18];
  float* out = (float*)d_out;

  unsigned short* u = (unsigned short*)d_ws;
  unsigned short* D1t  = u;
  unsigned short* D2t  = u + BCN;
  unsigned short* Qt   = u + 2 * BCN;
  unsigned short* Kt   = u + 3 * BCN;
  unsigned short* Vbb  = u + 4 * BCN;
  unsigned short* Ot    = D2t;         // D2t dead after v-gemm
  unsigned short* MoutT = Qt;          // Qt dead after attn
  unsigned short* HT    = Kt;          // Kt+Vbb dead after attn (2*BCN)
  unsigned short* Wqb  = u + 5 * BCN;
  unsigned short* Wkb  = Wqb + 65536;
  unsigned short* Wvb  = Wkb + 65536;
  unsigned short* Wmb  = Wvb + 65536;
  unsigned short* Wc1b = Wmb + 65536;
  unsigned short* Wc2b = Wc1b + 262144;

  dim3 blk(256);
  quantw_kernel<<<dim3(64, 6), blk, 0, stream>>>(
      Wq, Wk, Wv, Wm, Wc1, Wc2, Wqb, Wkb, Wvb, Wmb, Wc1b, Wc2b);
  trans_kernel<<<dim3(32, 4, 16), blk, 0, stream>>>(desc1, desc2, D1t, D2t);

  // Qt = [bh][n][64] bf16 of 0.125*(Wq desc1 + bq)
  gemm_kernel<256,0,256,0><<<dim3(16, 2, Bb), blk, 0, stream>>>(
      Wqb, D1t, nullptr, bq, nullptr,nullptr,nullptr,nullptr, Qt, 0.125f);
  // Kt = [bh][m][64]
  gemm_kernel<256,0,256,0><<<dim3(16, 2, Bb), blk, 0, stream>>>(
      Wkb, D2t, nullptr, bk, nullptr,nullptr,nullptr,nullptr, Kt, 1.0f);
  // Vb = [b][o][m] * weight_v
  gemm_kernel<256,0,256,1><<<dim3(16, 2, Bb), blk, 0, stream>>>(
      Wvb, D2t, nullptr, bv, wvv,nullptr,nullptr,nullptr, Vbb, 1.0f);
  // attention -> Ot [b][n][256] bf16
  attn_mfma_kernel<<<dim3(1024), blk, 0, stream>>>(Qt, Kt, Vbb, Ot);
  // MoutT = [b][n][256] bf16
  gemm_kernel<256,0,256,2><<<dim3(16, 2, Bb), blk, 0, stream>>>(
      Wmb, Ot, nullptr, bm, nullptr,nullptr,nullptr,nullptr, MoutT, 1.0f);
  // HT = [b][n][512] bf16 of relu(BN(Wc1 [desc1; mout] + bc1))
  gemm_kernel<256,256,512,3><<<dim3(16, 4, Bb), blk, 0, stream>>>(
      Wc1b, D1t, MoutT, bc1, bng,bnb,bnm,bnv, HT, 1.0f);
  // out = desc1 + Wc2 h + bc2  (f32)
  gemm_kernel<512,0,256,4><<<dim3(16, 2, Bb), blk, 0, stream>>>(
      Wc2b, HT, nullptr, bc2, desc1,nullptr,nullptr,nullptr, out, 1.0f);
}

// Round 15
// 298.400 us; speedup vs baseline: 1.3790x; 1.3790x over previous
//
#include <hip/hip_runtime.h>
#include <hip/hip_bf16.h>
#include <math.h>

// Problem constants (fixed by the reference).
constexpr int Bb = 8;
constexpr int Hh = 4;
constexpr int Nn = 2048;
constexpr int Mm = 2048;
constexpr size_t BCN = (size_t)Bb * 256 * Nn;   // 4,194,304 elements

typedef __attribute__((ext_vector_type(8))) short short8;
typedef __attribute__((ext_vector_type(4))) float f32x4;

__device__ __forceinline__ unsigned short bfu(float x) {
  __hip_bfloat16 b = __float2bfloat16(x);        // RNE
  return __builtin_bit_cast(unsigned short, b);
}

__device__ __forceinline__ void gload16(const unsigned short* g, unsigned short* l) {
  __builtin_amdgcn_global_load_lds(
      (const __attribute__((address_space(1))) unsigned int*)g,
      (__attribute__((address_space(3))) unsigned int*)l, 16, 0, 0);
}

// ---------------------------------------------------------------------------
// Weight quantization: f32 -> bf16 (Wq scaled by 0.125). One launch, 6 segs.
// ---------------------------------------------------------------------------
__global__ __launch_bounds__(256) void quantw_kernel(
    const float* __restrict__ s0, const float* __restrict__ s1,
    const float* __restrict__ s2, const float* __restrict__ s3,
    const float* __restrict__ s4, const float* __restrict__ s5,
    unsigned short* __restrict__ d0, unsigned short* __restrict__ d1,
    unsigned short* __restrict__ d2, unsigned short* __restrict__ d3,
    unsigned short* __restrict__ d4, unsigned short* __restrict__ d5)
{
  const int seg = blockIdx.y;
  const float* s; unsigned short* d; int cnt; float sc = 1.f;
  switch (seg) {
    case 0: s = s0; d = d0; cnt = 65536;  sc = 0.125f; break;
    case 1: s = s1; d = d1; cnt = 65536;  break;
    case 2: s = s2; d = d2; cnt = 65536;  break;
    case 3: s = s3; d = d3; cnt = 65536;  break;
    case 4: s = s4; d = d4; cnt = 262144; break;
    default: s = s5; d = d5; cnt = 131072; break;
  }
  for (int i = blockIdx.x * 256 + threadIdx.x; i < cnt / 4; i += 64 * 256) {
    float4 v = ((const float4*)s)[i];
    unsigned int lo = bfu(v.x * sc) | ((unsigned int)bfu(v.y * sc) << 16);
    unsigned int hi = bfu(v.z * sc) | ((unsigned int)bfu(v.w * sc) << 16);
    ((uint2*)d)[i] = make_uint2(lo, hi);
  }
}

// ---------------------------------------------------------------------------
// Transpose+quantize: desc [b][256][2048] f32 -> [b][2048][256] bf16.
// ---------------------------------------------------------------------------
__global__ __launch_bounds__(256) void trans_kernel(
    const float* __restrict__ S1, const float* __restrict__ S2,
    unsigned short* __restrict__ D1, unsigned short* __restrict__ D2)
{
  __shared__ float T[64][65];
  const int z = blockIdx.z, b = z & 7;
  const float* S = (z >> 3) ? S2 : S1;
  unsigned short* D = (z >> 3) ? D2 : D1;
  const int n0 = blockIdx.x * 64, c0 = blockIdx.y * 64;
  const int t = threadIdx.x, t4 = t >> 6, tl = t & 63;

  #pragma unroll
  for (int r = 0; r < 16; ++r) {
    int cl = r * 4 + t4;
    T[cl][tl] = S[((size_t)b * 256 + c0 + cl) * 2048 + n0 + tl];
  }
  __syncthreads();
  #pragma unroll
  for (int r = 0; r < 16; ++r) {
    int nl = r * 4 + t4;
    D[((size_t)b * 2048 + n0 + nl) * 256 + c0 + tl] = bfu(T[tl][nl]);
  }
}

// ---------------------------------------------------------------------------
// Merged Q/K/V projection GEMM (one dispatch, 768 blocks = 3 blocks/CU).
// mode = blockIdx.z>>3: 0 = Qt (TRANS, *0.125), 1 = Kt (TRANS), 2 = Vb (*wv).
// Same verified 128x128/BK=64 staging + XOR-swizzle structure as gemm_kernel.
// ---------------------------------------------------------------------------
__global__ __launch_bounds__(256) void qkv_kernel(
    const unsigned short* __restrict__ Wqb, const unsigned short* __restrict__ Wkb,
    const unsigned short* __restrict__ Wvb,
    const unsigned short* __restrict__ D1t, const unsigned short* __restrict__ D2t,
    const float* __restrict__ bq, const float* __restrict__ bk,
    const float* __restrict__ bv, const float* __restrict__ wvv,
    unsigned short* __restrict__ Qt, unsigned short* __restrict__ Kt,
    unsigned short* __restrict__ Vbb)
{
  constexpr int KT = 256;
  __shared__ unsigned short lds[2 * 128 * 64];
  unsigned short* Wl = lds;
  unsigned short* Xl = lds + 128 * 64;

  const int mode = blockIdx.z >> 3;
  const int b    = blockIdx.z & 7;
  const unsigned short* Wb = mode == 0 ? Wqb : (mode == 1 ? Wkb : Wvb);
  const unsigned short* X  = mode == 0 ? D1t : D2t;
  const float* bias        = mode == 0 ? bq  : (mode == 1 ? bk  : bv);

  const int t = threadIdx.x;
  const int w = t >> 6, l = t & 63;
  const int c = l & 15, h4 = l >> 4;
  const int n0 = blockIdx.x * 128;
  const int o0 = blockIdx.y * 128;
  const int wo = (w & 1) * 64, wn = (w >> 1) * 64;
  const int r8  = t >> 3;
  const int kgx = (t & 7) ^ (r8 & 7);

  const unsigned short* Xb = X + (size_t)b * 2048 * KT;

  f32x4 acc[4][4] = {};

  #pragma unroll 1
  for (int kt = 0; kt < 4; ++kt) {
    __syncthreads();
    #pragma unroll
    for (int q = 0; q < 4; ++q) {
      int row = q * 32 + r8;
      gload16(Wb + (size_t)(o0 + row) * KT + kt * 64 + kgx * 8, Wl + q * 2048 + w * 512);
      gload16(Xb + (size_t)(n0 + row) * KT + kt * 64 + kgx * 8, Xl + q * 2048 + w * 512);
    }
    __syncthreads();

    #pragma unroll
    for (int kk = 0; kk < 2; ++kk) {
      short8 wf[4], xf[4];
      #pragma unroll
      for (int f = 0; f < 4; ++f) {
        int row = wo + f * 16 + c;
        wf[f] = *(const short8*)((const char*)Wl + row * 128 + (((kk * 4 + h4) ^ (row & 7)) << 4));
      }
      #pragma unroll
      for (int f = 0; f < 4; ++f) {
        int row = wn + f * 16 + c;
        xf[f] = *(const short8*)((const char*)Xl + row * 128 + (((kk * 4 + h4) ^ (row & 7)) << 4));
      }
      if (mode != 2) {
        #pragma unroll
        for (int i = 0; i < 4; ++i)
          #pragma unroll
          for (int j = 0; j < 4; ++j)
            acc[i][j] = __builtin_amdgcn_mfma_f32_16x16x32_bf16(xf[i], wf[j], acc[i][j], 0, 0, 0);
      } else {
        #pragma unroll
        for (int i = 0; i < 4; ++i)
          #pragma unroll
          for (int j = 0; j < 4; ++j)
            acc[i][j] = __builtin_amdgcn_mfma_f32_16x16x32_bf16(wf[i], xf[j], acc[i][j], 0, 0, 0);
      }
    }
  }

  if (mode != 2) {                      // Qt/Kt: [b*H+h][n][64] bf16 (TRANS)
    float os = mode == 0 ? 0.125f : 1.0f;
    unsigned short* Y = mode == 0 ? Qt : Kt;
    #pragma unroll
    for (int j = 0; j < 4; ++j) {
      int og = o0 + wo + j * 16 + c;
      float bb = bias[og] * os;
      int hh = og >> 6, d = og & 63;
      unsigned short* Yp = Y + (((size_t)b * Hh + hh) * 2048) * 64 + d;
      #pragma unroll
      for (int i = 0; i < 4; ++i)
        #pragma unroll
        for (int r = 0; r < 4; ++r) {
          int ng = n0 + wn + i * 16 + h4 * 4 + r;
          Yp[(size_t)ng * 64] = bfu(acc[i][j][r] + bb);
        }
    }
  } else {                              // Vb: [b][o][m] bf16, *weight_v
    #pragma unroll
    for (int j = 0; j < 4; ++j) {
      int mg = n0 + wn + j * 16 + c;
      float sc = wvv[(size_t)b * 2048 + mg];
      #pragma unroll
      for (int i = 0; i < 4; ++i)
        #pragma unroll
        for (int r = 0; r < 4; ++r) {
          int og = o0 + wo + i * 16 + h4 * 4 + r;
          Vbb[((size_t)b * 256 + og) * 2048 + mg] = bfu((acc[i][j][r] + bias[og]) * sc);
        }
    }
  }
}

// ---------------------------------------------------------------------------
// Staged bf16 MFMA GEMM (round-7 verified), for Mout/C1/C2.
// EPI: 2 = M (bf16 [b][n][256], +bias); 3 = C1 (bf16 [b][n][512], BN+ReLU);
//      4 = C2 (f32 [b][o][n], +bias+residual)
// ---------------------------------------------------------------------------
template<int K1, int K2, int COUT, int EPI>
__global__ __launch_bounds__(256) void gemm_kernel(
    const unsigned short* __restrict__ Wb,
    const unsigned short* __restrict__ X1, const unsigned short* __restrict__ X2,
    const float* __restrict__ bias,
    const float* __restrict__ p0, const float* __restrict__ p1,
    const float* __restrict__ p2, const float* __restrict__ p3,
    void* __restrict__ Yv)
{
  constexpr int KT = K1 + K2;
  constexpr bool TRANS = (EPI == 2 || EPI == 3);
  __shared__ unsigned short lds[2 * 128 * 64];
  unsigned short* Wl = lds;
  unsigned short* Xl = lds + 128 * 64;

  const int t = threadIdx.x;
  const int w = t >> 6, l = t & 63;
  const int c = l & 15, h4 = l >> 4;
  const int n0 = blockIdx.x * 128;
  const int o0 = blockIdx.y * 128;
  const int b  = blockIdx.z;
  const int wo = (w & 1) * 64, wn = (w >> 1) * 64;

  const int r8  = t >> 3;
  const int kgx = (t & 7) ^ (r8 & 7);

  const unsigned short* Xb1 = X1 + (size_t)b * 2048 * K1;

  f32x4 acc[4][4] = {};

  #pragma unroll 1
  for (int kt = 0; kt < KT / 64; ++kt) {
    __syncthreads();
    #pragma unroll
    for (int q = 0; q < 4; ++q) {
      int row = q * 32 + r8;
      gload16(Wb + (size_t)(o0 + row) * KT + kt * 64 + kgx * 8,
              Wl + q * 2048 + w * 512);
      const unsigned short* src;
      if constexpr (K2 == 0) {
        src = Xb1 + (size_t)(n0 + row) * K1 + kt * 64 + kgx * 8;
      } else {
        src = (kt * 64 < K1)
          ? Xb1 + (size_t)(n0 + row) * K1 + kt * 64 + kgx * 8
          : X2 + ((size_t)b * 2048 + n0 + row) * K2 + (kt * 64 - K1) + kgx * 8;
      }
      gload16(src, Xl + q * 2048 + w * 512);
    }
    __syncthreads();

    #pragma unroll
    for (int kk = 0; kk < 2; ++kk) {
      short8 wf[4], xf[4];
      #pragma unroll
      for (int f = 0; f < 4; ++f) {
        int row = wo + f * 16 + c;
        wf[f] = *(const short8*)((const char*)Wl + row * 128 + (((kk * 4 + h4) ^ (row & 7)) << 4));
      }
      #pragma unroll
      for (int f = 0; f < 4; ++f) {
        int row = wn + f * 16 + c;
        xf[f] = *(const short8*)((const char*)Xl + row * 128 + (((kk * 4 + h4) ^ (row & 7)) << 4));
      }
      #pragma unroll
      for (int i = 0; i < 4; ++i)
        #pragma unroll
        for (int j = 0; j < 4; ++j) {
          if constexpr (TRANS)
            acc[i][j] = __builtin_amdgcn_mfma_f32_16x16x32_bf16(xf[i], wf[j], acc[i][j], 0, 0, 0);
          else
            acc[i][j] = __builtin_amdgcn_mfma_f32_16x16x32_bf16(wf[i], xf[j], acc[i][j], 0, 0, 0);
        }
    }
  }

  if constexpr (EPI == 2) {             // MoutT: [b][n][256] bf16
    unsigned short* Y = (unsigned short*)Yv;
    #pragma unroll
    for (int j = 0; j < 4; ++j) {
      int og = o0 + wo + j * 16 + c;
      float bb = bias[og];
      #pragma unroll
      for (int i = 0; i < 4; ++i)
        #pragma unroll
        for (int r = 0; r < 4; ++r) {
          int ng = n0 + wn + i * 16 + h4 * 4 + r;
          Y[((size_t)b * 2048 + ng) * 256 + og] = bfu(acc[i][j][r] + bb);
        }
    }
  } else if constexpr (EPI == 3) {      // HT: [b][n][512] bf16, BN+ReLU
    unsigned short* Y = (unsigned short*)Yv;
    #pragma unroll
    for (int j = 0; j < 4; ++j) {
      int og = o0 + wo + j * 16 + c;
      float bb  = bias[og];
      float inv = p0[og] / sqrtf(p3[og] + 1e-5f);
      float add = p1[og] - p2[og] * inv;
      #pragma unroll
      for (int i = 0; i < 4; ++i)
        #pragma unroll
        for (int r = 0; r < 4; ++r) {
          int ng = n0 + wn + i * 16 + h4 * 4 + r;
          float v = fmaxf((acc[i][j][r] + bb) * inv + add, 0.f);
          Y[((size_t)b * 2048 + ng) * 512 + og] = bfu(v);
        }
    }
  } else {                              // out: [b][o][n] f32, +bias+residual
    float* Y = (float*)Yv;
    #pragma unroll
    for (int j = 0; j < 4; ++j) {
      int ng = n0 + wn + j * 16 + c;
      #pragma unroll
      for (int i = 0; i < 4; ++i)
        #pragma unroll
        for (int r = 0; r < 4; ++r) {
          int og = o0 + wo + i * 16 + h4 * 4 + r;
          size_t idx = ((size_t)b * 256 + og) * 2048 + ng;
          Y[idx] = acc[i][j][r] + bias[og] + p0[idx];
        }
    }
  }
}

// ---------------------------------------------------------------------------
// MFMA flash attention — round-7 structure (32 n/wave, 512 blocks) + ping-pong
// K prefetch (one tile ahead) + s_setprio around MFMA clusters.
// ---------------------------------------------------------------------------
__global__ __launch_bounds__(256) void attn_mfma_kernel(
    const unsigned short* __restrict__ Qt, const unsigned short* __restrict__ Ktp,
    const unsigned short* __restrict__ Vb, unsigned short* __restrict__ Ot)
{
  const int id  = blockIdx.x;
  const int xcd = id & 7;
  const int s8  = id >> 3;
  const int bh  = xcd + 8 * (s8 >> 4);
  const int nb  = s8 & 15;
  const int wv  = threadIdx.x >> 6;
  const int l   = threadIdx.x & 63;
  const int c   = l & 15;
  const int h   = l >> 4;
  const int n0  = nb * 128 + wv * 32;

  const unsigned short* Qw = Qt + ((size_t)bh * Nn + n0) * 64;
  const unsigned short* Kb = Ktp + (size_t)bh * Mm * 64;
  const unsigned short* Vw = Vb + (size_t)bh * 64 * Mm;

  __shared__ unsigned short Pl[4][32 * 64];
  char* P = (char*)Pl[wv];

  short8 qf[2][2];
  #pragma unroll
  for (int j = 0; j < 2; ++j)
    #pragma unroll
    for (int ks = 0; ks < 2; ++ks)
      qf[j][ks] = *(const short8*)(Qw + ((size_t)(j*16 + c)) * 64 + ks*32 + h*8);

  f32x4 acc[4][2];
  #pragma unroll
  for (int d = 0; d < 4; ++d)
    #pragma unroll
    for (int j = 0; j < 2; ++j) acc[d][j] = (f32x4){0.f,0.f,0.f,0.f};
  float rowM[2] = {-1e30f, -1e30f};
  float rowL[2] = {0.f, 0.f};

  short8 kfA[4][2], kfB[4][2];

  auto loadK = [&](short8 (&kf)[4][2], int m0) {
    #pragma unroll
    for (int g = 0; g < 4; ++g)
      #pragma unroll
      for (int ks = 0; ks < 2; ++ks)
        kf[g][ks] = *(const short8*)(Kb + ((size_t)(m0 + g*16 + c)) * 64 + ks*32 + h*8);
  };

  auto tile = [&](short8 (&kf)[4][2], int m0) {
    // S^T[m][n]: lane holds col n = j*16+c, rows m = m0 + g*16 + h*4 + r
    f32x4 sc4[4][2];
    __builtin_amdgcn_s_setprio(1);
    #pragma unroll
    for (int g = 0; g < 4; ++g)
      #pragma unroll
      for (int j = 0; j < 2; ++j) {
        f32x4 z = (f32x4){0.f,0.f,0.f,0.f};
        z = __builtin_amdgcn_mfma_f32_16x16x32_bf16(kf[g][0], qf[j][0], z, 0, 0, 0);
        z = __builtin_amdgcn_mfma_f32_16x16x32_bf16(kf[g][1], qf[j][1], z, 0, 0, 0);
        sc4[g][j] = z;
      }
    __builtin_amdgcn_s_setprio(0);

    // V A-frags issued before softmax (latency hides under it).
    short8 vf[4][2];
    #pragma unroll
    for (int db = 0; db < 4; ++db)
      #pragma unroll
      for (int ks = 0; ks < 2; ++ks)
        vf[db][ks] = *(const short8*)(Vw + ((size_t)(db*16 + c)) * Mm + m0 + ks*32 + h*8);

    #pragma unroll
    for (int j = 0; j < 2; ++j) {
      float mx = -1e30f;
      #pragma unroll
      for (int g = 0; g < 4; ++g)
        #pragma unroll
        for (int r = 0; r < 4; ++r) mx = fmaxf(mx, sc4[g][j][r]);
      mx = fmaxf(mx, __shfl_xor(mx, 16));
      mx = fmaxf(mx, __shfl_xor(mx, 32));
      float nm = fmaxf(rowM[j], mx);
      float corr = __expf(rowM[j] - nm);
      rowM[j] = nm;
      float sum = 0.f;
      #pragma unroll
      for (int g = 0; g < 4; ++g)
        #pragma unroll
        for (int r = 0; r < 4; ++r) {
          float e = __expf(sc4[g][j][r] - nm);
          sc4[g][j][r] = e;
          sum += e;
        }
      sum += __shfl_xor(sum, 16);
      sum += __shfl_xor(sum, 32);
      rowL[j] = rowL[j] * corr + sum;
      #pragma unroll
      for (int db = 0; db < 4; ++db)
        #pragma unroll
        for (int r = 0; r < 4; ++r) acc[db][j][r] *= corr;

      #pragma unroll
      for (int g = 0; g < 4; ++g) {
        unsigned int lo = ((unsigned int)bfu(sc4[g][j][1]) << 16) | bfu(sc4[g][j][0]);
        unsigned int hi = ((unsigned int)bfu(sc4[g][j][3]) << 16) | bfu(sc4[g][j][2]);
        int off = (j*16 + c) * 128 + g*32 + h*8;
        off ^= (c & 7) << 4;
        *(uint2*)(P + off) = make_uint2(lo, hi);
      }
    }

    #pragma unroll
    for (int j = 0; j < 2; ++j) {
      short8 pf[2];
      #pragma unroll
      for (int ks = 0; ks < 2; ++ks) {
        int off = (j*16 + c) * 128 + ks*64 + h*16;
        off ^= (c & 7) << 4;
        pf[ks] = *(const short8*)(P + off);
      }
      __builtin_amdgcn_s_setprio(1);
      #pragma unroll
      for (int db = 0; db < 4; ++db) {
        acc[db][j] = __builtin_amdgcn_mfma_f32_16x16x32_bf16(vf[db][0], pf[0], acc[db][j], 0, 0, 0);
        acc[db][j] = __builtin_amdgcn_mfma_f32_16x16x32_bf16(vf[db][1], pf[1], acc[db][j], 0, 0, 0);
      }
      __builtin_amdgcn_s_setprio(0);
    }
  };

  loadK(kfA, 0);
  #pragma unroll 1
  for (int m0 = 0; m0 < Mm; m0 += 128) {
    loadK(kfB, m0 + 64);                     // prefetch t+1 (full tile ahead)
    tile(kfA, m0);
    loadK(kfA, (m0 + 128) & (Mm - 1));       // prefetch t+2 (wraps harmlessly at end)
    tile(kfB, m0 + 64);
  }

  const float invl[2] = {1.f / rowL[0], 1.f / rowL[1]};
  unsigned short* Ob = Ot + ((size_t)(bh >> 2) * Nn) * 256 + (bh & 3) * 64;
  #pragma unroll
  for (int db = 0; db < 4; ++db)
    #pragma unroll
    for (int j = 0; j < 2; ++j) {
      unsigned int lo = ((unsigned int)bfu(acc[db][j][1] * invl[j]) << 16) | bfu(acc[db][j][0] * invl[j]);
      unsigned int hi = ((unsigned int)bfu(acc[db][j][3] * invl[j]) << 16) | bfu(acc[db][j][2] * invl[j]);
      *(uint2*)(Ob + (size_t)(n0 + j*16 + c) * 256 + db*16 + h*4) = make_uint2(lo, hi);
    }
}

// ---------------------------------------------------------------------------
extern "C" void kernel_launch(void* const* d_in, const int* in_sizes, int n_in,
                              void* d_out, int out_size, void* d_ws, size_t ws_size,
                              hipStream_t stream)
{
  (void)in_sizes; (void)n_in; (void)out_size; (void)ws_size;
  const float* desc1 = (const float*)d_in[0];
  const float* desc2 = (const float*)d_in[1];
  const float* wvv   = (const float*)d_in[2];
  const float* Wq  = (const float*)d_in[3];  const float* bq  = (const float*)d_in[4];
  const float* Wk  = (const float*)d_in[5];  const float* bk  = (const float*)d_in[6];
  const float* Wv  = (const float*)d_in[7];  const float* bv  = (const float*)d_in[8];
  const float* Wm  = (const float*)d_in[9];  const float* bm  = (const float*)d_in[10];
  const float* Wc1 = (const float*)d_in[11]; const float* bc1 = (const float*)d_in[12];
  const float* bng = (const float*)d_in[13]; const float* bnb = (const float*)d_in[14];
  const float* bnm = (const float*)d_in[15]; const float* bnv = (const float*)d_in[16];
  const float* Wc2 = (const float*)d_in[17]; const float* bc2 = (const float*)d_in[18];
  float* out = (float*)d_out;

  unsigned short* u = (unsigned short*)d_ws;
  unsigned short* D1t  = u;
  unsigned short* D2t  = u + BCN;
  unsigned short* Qt   = u + 2 * BCN;
  unsigned short* Kt   = u + 3 * BCN;
  unsigned short* Vbb  = u + 4 * BCN;
  unsigned short* Ot    = D2t;         // D2t dead after qkv
  unsigned short* MoutT = Qt;          // Qt dead after attn
  unsigned short* HT    = Kt;          // Kt+Vbb dead after attn (2*BCN)
  unsigned short* Wqb  = u + 5 * BCN;
  unsigned short* Wkb  = Wqb + 65536;
  unsigned short* Wvb  = Wkb + 65536;
  unsigned short* Wmb  = Wvb + 65536;
  unsigned short* Wc1b = Wmb + 65536;
  unsigned short* Wc2b = Wc1b + 262144;

  dim3 blk(256);
  quantw_kernel<<<dim3(64, 6), blk, 0, stream>>>(
      Wq, Wk, Wv, Wm, Wc1, Wc2, Wqb, Wkb, Wvb, Wmb, Wc1b, Wc2b);
  trans_kernel<<<dim3(32, 4, 16), blk, 0, stream>>>(desc1, desc2, D1t, D2t);

  // Qt/Kt/Vb in one dispatch (768 blocks = 3 blocks/CU)
  qkv_kernel<<<dim3(16, 2, 24), blk, 0, stream>>>(
      Wqb, Wkb, Wvb, D1t, D2t, bq, bk, bv, wvv, Qt, Kt, Vbb);
  // attention -> Ot [b][n][256] bf16
  attn_mfma_kernel<<<dim3(512), blk, 0, stream>>>(Qt, Kt, Vbb, Ot);
  // MoutT = [b][n][256] bf16
  gemm_kernel<256,0,256,2><<<dim3(16, 2, Bb), blk, 0, stream>>>(
      Wmb, Ot, nullptr, bm, nullptr,nullptr,nullptr,nullptr, MoutT);
  // HT = [b][n][512] bf16 of relu(BN(Wc1 [desc1; mout] + bc1))
  gemm_kernel<256,256,512,3><<<dim3(16, 4, Bb), blk, 0, stream>>>(
      Wc1b, D1t, MoutT, bc1, bng,bnb,bnm,bnv, HT);
  // out = desc1 + Wc2 h + bc2  (f32)
  gemm_kernel<512,0,256,4><<<dim3(16, 2, Bb), blk, 0, stream>>>(
      Wc2b, HT, nullptr, bc2, desc1,nullptr,nullptr,nullptr, out);
}